// Round 6
// baseline (301.003 us; speedup 1.0000x reference)
//
#include <hip/hip_runtime.h>
#include <hip/hip_bf16.h>
#include <stdint.h>

#define M_DIM 4096
#define N_DIM 4096
#define K_DIM 4096
#define NGROUPS (N_DIM * K_DIM / 8)

typedef __attribute__((ext_vector_type(4))) float f32x4;
typedef __attribute__((ext_vector_type(8))) short bf16x8;
typedef __attribute__((ext_vector_type(4))) int   i32x4;

__device__ __forceinline__ ushort f2bf(float f) {
  union { float f; uint32_t u; } v; v.f = f;
  uint32_t r = v.u + 0x7FFFu + ((v.u >> 16) & 1u);
  return (ushort)(r >> 16);
}

// ---------------- pre-pass 1: dequant 4-bit W -> bf16 [N][K] ----------------
__global__ void k_dequant_w(const int* __restrict__ wp, const float* __restrict__ wsc,
                            const float* __restrict__ wbs, ushort* __restrict__ W) {
  const int g = blockIdx.x * 256 + threadIdx.x;
  i32x4 p = *(const i32x4*)(wp + (size_t)g * 4);
  const float s = wsc[g];
  const float b = wbs[g];
  bf16x8 o;
#pragma unroll
  for (int j = 0; j < 4; ++j) {
    const float lo = (float)(p[j] & 15)        * s + b;
    const float hi = (float)((p[j] >> 4) & 15) * s + b;
    o[2 * j]     = (short)f2bf(lo);
    o[2 * j + 1] = (short)f2bf(hi);
  }
  *(bf16x8*)(W + (size_t)g * 8) = o;
}

// ---------------- pre-pass 2: cast x fp32 -> bf16 [M][K] ----------------
__global__ void k_cvt_x(const float* __restrict__ x, ushort* __restrict__ X) {
  const int t = blockIdx.x * 256 + threadIdx.x;
  f32x4 a = *(const f32x4*)(x + (size_t)t * 8);
  f32x4 b = *(const f32x4*)(x + (size_t)t * 8 + 4);
  bf16x8 o;
#pragma unroll
  for (int j = 0; j < 4; ++j) {
    o[j]     = (short)f2bf(a[j]);
    o[4 + j] = (short)f2bf(b[j]);
  }
  *(bf16x8*)(X + (size_t)t * 8) = o;
}

// ---------------- main: 256x256, BK=64, 8 waves, register-pipelined 4-phase -
// Frags for phase p's MFMA are read in phase p-1 (cross-tile at ph3), so the
// MFMA cluster never waits on this phase's ds_reads. Staging of tile t+1
// issues at ph0(A)/ph1(B); own-wave vmcnt(0)+s_barrier at ph3 entry is the
// only correctness sync (then ph3 reads tile t+1's first frags from buf b^1
// overlapped with MFMA Q10). Swizzle as R2 (verified: conflicts == 0).

#define GLD(src, dst) __builtin_amdgcn_global_load_lds(                        \
    (const __attribute__((address_space(1))) void*)(src),                      \
    (__attribute__((address_space(3))) void*)(dst), 16, 0, 0)

__global__ __launch_bounds__(512, 2) void k_gemm_8ph(
    const ushort* __restrict__ A, const ushort* __restrict__ B,
    const float* __restrict__ bias, float* __restrict__ C) {
  __shared__ ushort sA[2][256 * 64];
  __shared__ ushort sB[2][256 * 64];
  const int tid  = threadIdx.x;
  const int lane = tid & 63;
  const int wid  = tid >> 6;
  const int wr   = wid >> 2;   // 0..1  (M)
  const int wc   = wid & 3;    // 0..3  (N)
  const int bm = blockIdx.x >> 4;
  const int bn = blockIdx.x & 15;

  const ushort* Ab = A + (size_t)bm * 256 * K_DIM;
  const ushort* Bb = B + (size_t)bn * 256 * K_DIM;

  // staging: 4 chunks/thread/operand; source col-chunk pre-swizzled (R2).
  const int srow = tid >> 3;
  const int scc  = (tid & 7) ^ ((tid >> 3) & 7);
  const int dofs = (tid >> 6) * 64 * 8;  // wave-uniform chunk base (ushorts)

  // fragment read geometry (swizzled)
  const int l15   = lane & 15;
  const int kx    = (lane >> 4) * 8;
  const int xsw   = (lane & 7) << 3;
  const int kidx0 = (0 * 32 + kx) ^ xsw;
  const int kidx1 = (1 * 32 + kx) ^ xsw;
  const int abase = (wr * 128 + l15) * 64;
  const int bbase = (wc * 64 + l15) * 64;

  f32x4 acc[8][4] = {};

#define STAGE_A(buf, kko)                                                      \
  _Pragma("unroll") for (int j = 0; j < 4; ++j)                                \
      GLD(Ab + (size_t)(j * 64 + srow) * K_DIM + (kko) + scc * 8,              \
          &sA[buf][j * 4096 + dofs]);
#define STAGE_B(buf, kko)                                                      \
  _Pragma("unroll") for (int j = 0; j < 4; ++j)                                \
      GLD(Bb + (size_t)(j * 64 + srow) * K_DIM + (kko) + scc * 8,              \
          &sB[buf][j * 4096 + dofs]);

  // prologue: stage tile 0 into buf 0, then preload its A0/B0 fragments
  STAGE_A(0, 0);
  STAGE_B(0, 0);
  __syncthreads();

  bf16x8 af0[4][2], af1[4][2], bfA[2][2], bfB[2][2];
#pragma unroll
  for (int m = 0; m < 4; ++m) {
    af0[m][0] = *(const bf16x8*)(sA[0] + abase + m * 1024 + kidx0);
    af0[m][1] = *(const bf16x8*)(sA[0] + abase + m * 1024 + kidx1);
  }
#pragma unroll
  for (int n = 0; n < 2; ++n) {
    bfA[n][0] = *(const bf16x8*)(sB[0] + bbase + n * 1024 + kidx0);
    bfA[n][1] = *(const bf16x8*)(sB[0] + bbase + n * 1024 + kidx1);
  }

  for (int t = 0; t < 64; ++t) {
    const int b  = t & 1;
    const int kk = t * 64;
    const ushort* sAb = sA[b];
    const ushort* sBb = sB[b];
    const ushort* sAn = sA[b ^ 1];
    const ushort* sBn = sB[b ^ 1];

    // ---- phase 0: stage A(t+1); read bfB (B rows +32..63); MFMA Q00
    if (t < 63) { STAGE_A(b ^ 1, kk + 64); }
#pragma unroll
    for (int n = 0; n < 2; ++n) {
      bfB[n][0] = *(const bf16x8*)(sBb + bbase + (2 + n) * 1024 + kidx0);
      bfB[n][1] = *(const bf16x8*)(sBb + bbase + (2 + n) * 1024 + kidx1);
    }
    __builtin_amdgcn_s_setprio(1);
#pragma unroll
    for (int m = 0; m < 4; ++m)
#pragma unroll
      for (int n = 0; n < 2; ++n)
#pragma unroll
        for (int kc = 0; kc < 2; ++kc)
          acc[m][n] = __builtin_amdgcn_mfma_f32_16x16x32_bf16(
              af0[m][kc], bfA[n][kc], acc[m][n], 0, 0, 0);
    __builtin_amdgcn_s_setprio(0);
    __builtin_amdgcn_s_barrier();

    // ---- phase 1: stage B(t+1); read af1 (A rows +64..127); MFMA Q01
    if (t < 63) { STAGE_B(b ^ 1, kk + 64); }
#pragma unroll
    for (int m = 0; m < 4; ++m) {
      af1[m][0] = *(const bf16x8*)(sAb + abase + (4 + m) * 1024 + kidx0);
      af1[m][1] = *(const bf16x8*)(sAb + abase + (4 + m) * 1024 + kidx1);
    }
    __builtin_amdgcn_s_setprio(1);
#pragma unroll
    for (int m = 0; m < 4; ++m)
#pragma unroll
      for (int n = 0; n < 2; ++n)
#pragma unroll
        for (int kc = 0; kc < 2; ++kc)
          acc[m][2 + n] = __builtin_amdgcn_mfma_f32_16x16x32_bf16(
              af0[m][kc], bfB[n][kc], acc[m][2 + n], 0, 0, 0);
    __builtin_amdgcn_s_setprio(0);
    __builtin_amdgcn_s_barrier();

    // ---- phase 2: MFMA Q11 (pure compute)
    __builtin_amdgcn_s_setprio(1);
#pragma unroll
    for (int m = 0; m < 4; ++m)
#pragma unroll
      for (int n = 0; n < 2; ++n)
#pragma unroll
        for (int kc = 0; kc < 2; ++kc)
          acc[4 + m][2 + n] = __builtin_amdgcn_mfma_f32_16x16x32_bf16(
              af1[m][kc], bfB[n][kc], acc[4 + m][2 + n], 0, 0, 0);
    __builtin_amdgcn_s_setprio(0);

    // ---- phase 3: staging guarantee, MFMA Q10 ∥ preload next tile A0/B0
    if (t < 63) { asm volatile("s_waitcnt vmcnt(0)" ::: "memory"); }
    __builtin_amdgcn_s_barrier();
    asm volatile("" ::: "memory");
    __builtin_amdgcn_s_setprio(1);
#pragma unroll
    for (int m = 0; m < 4; ++m)
#pragma unroll
      for (int n = 0; n < 2; ++n)
#pragma unroll
        for (int kc = 0; kc < 2; ++kc)
          acc[4 + m][n] = __builtin_amdgcn_mfma_f32_16x16x32_bf16(
              af1[m][kc], bfA[n][kc], acc[4 + m][n], 0, 0, 0);
    __builtin_amdgcn_s_setprio(0);
    if (t < 63) {
#pragma unroll
      for (int m = 0; m < 4; ++m) {
        af0[m][0] = *(const bf16x8*)(sAn + abase + m * 1024 + kidx0);
        af0[m][1] = *(const bf16x8*)(sAn + abase + m * 1024 + kidx1);
      }
#pragma unroll
      for (int n = 0; n < 2; ++n) {
        bfA[n][0] = *(const bf16x8*)(sBn + bbase + n * 1024 + kidx0);
        bfA[n][1] = *(const bf16x8*)(sBn + bbase + n * 1024 + kidx1);
      }
    }
  }

  // epilogue: C/D layout col=lane&15, row=(lane>>4)*4+reg (m89-verified)
  const int fr = lane & 15;
  const int fq = lane >> 4;
  const int growbase = bm * 256 + wr * 128;
  const int gcolbase = bn * 256 + wc * 64;
#pragma unroll
  for (int ni = 0; ni < 4; ++ni) {
    const int col = gcolbase + ni * 16 + fr;
    const float bv = bias[col];
#pragma unroll
    for (int mi = 0; mi < 8; ++mi) {
      float* cp = C + (size_t)(growbase + mi * 16 + fq * 4) * N_DIM + col;
#pragma unroll
      for (int r = 0; r < 4; ++r)
        cp[(size_t)r * N_DIM] = acc[mi][ni][r] + bv;
    }
  }
}

// ---------------- fallback (only if ws too small): fused naive fp32 ---------
__global__ void k_fallback(const float* __restrict__ x, const int* __restrict__ wp,
                           const float* __restrict__ wsc, const float* __restrict__ wbs,
                           const float* __restrict__ bias, float* __restrict__ y) {
  const int m = blockIdx.x;
  const int n = blockIdx.y * 256 + threadIdx.x;
  const float* xr = x + (size_t)m * K_DIM;
  const int gbase = n * (K_DIM / 8);
  float acc = 0.f;
  for (int g = 0; g < K_DIM / 8; ++g) {
    i32x4 p = *(const i32x4*)(wp + (size_t)(gbase + g) * 4);
    const float s = wsc[gbase + g];
    const float b = wbs[gbase + g];
    const float* xk = xr + g * 8;
#pragma unroll
    for (int j = 0; j < 4; ++j) {
      acc += ((float)(p[j] & 15)        * s + b) * xk[2 * j];
      acc += ((float)((p[j] >> 4) & 15) * s + b) * xk[2 * j + 1];
    }
  }
  y[(size_t)m * N_DIM + n] = acc + bias[n];
}

extern "C" void kernel_launch(void* const* d_in, const int* in_sizes, int n_in,
                              void* d_out, int out_size, void* d_ws, size_t ws_size,
                              hipStream_t stream) {
  const float* x    = (const float*)d_in[0];
  const int*   wp   = (const int*)d_in[1];
  const float* wsc  = (const float*)d_in[2];
  const float* wbs  = (const float*)d_in[3];
  const float* bias = (const float*)d_in[4];
  float* y = (float*)d_out;

  const size_t wbytes = (size_t)N_DIM * K_DIM * sizeof(ushort);
  const size_t xbytes = (size_t)M_DIM * K_DIM * sizeof(ushort);

  if (ws_size >= wbytes + xbytes) {
    ushort* Wbf = (ushort*)d_ws;
    ushort* Xbf = (ushort*)((char*)d_ws + wbytes);
    k_dequant_w<<<NGROUPS / 256, 256, 0, stream>>>(wp, wsc, wbs, Wbf);
    k_cvt_x<<<(M_DIM * K_DIM / 8) / 256, 256, 0, stream>>>(x, Xbf);
    k_gemm_8ph<<<16 * 16, 512, 0, stream>>>(Xbf, Wbf, bias, y);
  } else {
    k_fallback<<<dim3(M_DIM, N_DIM / 256), 256, 0, stream>>>(x, wp, wsc, wbs, bias, y);
  }
}

// Round 7
// 296.993 us; speedup vs baseline: 1.0135x; 1.0135x over previous
//
#include <hip/hip_runtime.h>
#include <hip/hip_bf16.h>
#include <stdint.h>

#define M_DIM 4096
#define N_DIM 4096
#define K_DIM 4096
#define NGROUPS (N_DIM * K_DIM / 8)

typedef __attribute__((ext_vector_type(4))) float f32x4;
typedef __attribute__((ext_vector_type(8))) short bf16x8;
typedef __attribute__((ext_vector_type(4))) int   i32x4;

__device__ __forceinline__ ushort f2bf(float f) {
  union { float f; uint32_t u; } v; v.f = f;
  uint32_t r = v.u + 0x7FFFu + ((v.u >> 16) & 1u);
  return (ushort)(r >> 16);
}

// ---------------- pre-pass 1: dequant 4-bit W -> bf16 [N][K] ----------------
__global__ void k_dequant_w(const int* __restrict__ wp, const float* __restrict__ wsc,
                            const float* __restrict__ wbs, ushort* __restrict__ W) {
  const int g = blockIdx.x * 256 + threadIdx.x;
  i32x4 p = *(const i32x4*)(wp + (size_t)g * 4);
  const float s = wsc[g];
  const float b = wbs[g];
  bf16x8 o;
#pragma unroll
  for (int j = 0; j < 4; ++j) {
    const float lo = (float)(p[j] & 15)        * s + b;
    const float hi = (float)((p[j] >> 4) & 15) * s + b;
    o[2 * j]     = (short)f2bf(lo);
    o[2 * j + 1] = (short)f2bf(hi);
  }
  *(bf16x8*)(W + (size_t)g * 8) = o;
}

// ---------------- pre-pass 2: cast x fp32 -> bf16 [M][K] ----------------
__global__ void k_cvt_x(const float* __restrict__ x, ushort* __restrict__ X) {
  const int t = blockIdx.x * 256 + threadIdx.x;
  f32x4 a = *(const f32x4*)(x + (size_t)t * 8);
  f32x4 b = *(const f32x4*)(x + (size_t)t * 8 + 4);
  bf16x8 o;
#pragma unroll
  for (int j = 0; j < 4; ++j) {
    o[j]     = (short)f2bf(a[j]);
    o[4 + j] = (short)f2bf(b[j]);
  }
  *(bf16x8*)(X + (size_t)t * 8) = o;
}

// ---------------- main: 256x256, BK=64, 8 waves, m201-style phase interleave
// Per phase: {ds_reads feeding THIS phase's MFMA; one STAGE; sched_barrier;
// s_barrier; setprio(1); 16 MFMA; setprio(0); s_barrier}. Read latency drains
// during the barrier wait; waves de-skew so LDS pipe overlaps matrix pipe.
// Tile-granular dbuf; ph3 vmcnt(0) (loads 2-3 phases old) + barrier is the
// only staging-confirm sync. Swizzle as R4 (measured conflicts == 0).

#define GLD(src, dst) __builtin_amdgcn_global_load_lds(                        \
    (const __attribute__((address_space(1))) void*)(src),                      \
    (__attribute__((address_space(3))) void*)(dst), 16, 0, 0)

__global__ __launch_bounds__(512, 2) void k_gemm_8ph(
    const ushort* __restrict__ A, const ushort* __restrict__ B,
    const float* __restrict__ bias, float* __restrict__ C) {
  __shared__ ushort sA[2][256 * 64];
  __shared__ ushort sB[2][256 * 64];
  const int tid  = threadIdx.x;
  const int lane = tid & 63;
  const int wid  = tid >> 6;
  const int wr   = wid >> 2;   // 0..1  (M)
  const int wc   = wid & 3;    // 0..3  (N)
  const int bm = blockIdx.x >> 4;
  const int bn = blockIdx.x & 15;

  const ushort* Ab = A + (size_t)bm * 256 * K_DIM;
  const ushort* Bb = B + (size_t)bn * 256 * K_DIM;

  // staging: 4 chunks/thread/operand; source col-chunk pre-swizzled.
  const int srow = tid >> 3;
  const int scc  = (tid & 7) ^ ((tid >> 3) & 7);
  const int dofs = (tid >> 6) * 64 * 8;  // wave-uniform chunk base (ushorts)

  // fragment read geometry (swizzled)
  const int l15   = lane & 15;
  const int kx    = (lane >> 4) * 8;
  const int xsw   = (lane & 7) << 3;
  const int kidx0 = (0 * 32 + kx) ^ xsw;
  const int kidx1 = (1 * 32 + kx) ^ xsw;
  const int abase = (wr * 128 + l15) * 64;
  const int bbase = (wc * 64 + l15) * 64;

  f32x4 acc[8][4] = {};

#define STAGE_A(buf, kko)                                                      \
  _Pragma("unroll") for (int j = 0; j < 4; ++j)                                \
      GLD(Ab + (size_t)(j * 64 + srow) * K_DIM + (kko) + scc * 8,              \
          &sA[buf][j * 4096 + dofs]);
#define STAGE_B(buf, kko)                                                      \
  _Pragma("unroll") for (int j = 0; j < 4; ++j)                                \
      GLD(Bb + (size_t)(j * 64 + srow) * K_DIM + (kko) + scc * 8,              \
          &sB[buf][j * 4096 + dofs]);

  // prologue: stage tile 0 into buf 0
  STAGE_A(0, 0);
  STAGE_B(0, 0);
  __syncthreads();

  bf16x8 af0[4][2], af1[4][2], bfA[2][2], bfB[2][2];

  for (int t = 0; t < 64; ++t) {
    const int b  = t & 1;
    const int kk = t * 64;
    const ushort* sAb = sA[b];
    const ushort* sBb = sB[b];

    // ---- phase 0: reads af0(8)+bfA(4); STAGE_A(t+1); bar; MFMA Q00
#pragma unroll
    for (int m = 0; m < 4; ++m) {
      af0[m][0] = *(const bf16x8*)(sAb + abase + m * 1024 + kidx0);
      af0[m][1] = *(const bf16x8*)(sAb + abase + m * 1024 + kidx1);
    }
#pragma unroll
    for (int n = 0; n < 2; ++n) {
      bfA[n][0] = *(const bf16x8*)(sBb + bbase + n * 1024 + kidx0);
      bfA[n][1] = *(const bf16x8*)(sBb + bbase + n * 1024 + kidx1);
    }
    if (t < 63) { STAGE_A(b ^ 1, kk + 64); }
    __builtin_amdgcn_sched_barrier(0);
    __builtin_amdgcn_s_barrier();
    __builtin_amdgcn_s_setprio(1);
#pragma unroll
    for (int m = 0; m < 4; ++m)
#pragma unroll
      for (int n = 0; n < 2; ++n)
#pragma unroll
        for (int kc = 0; kc < 2; ++kc)
          acc[m][n] = __builtin_amdgcn_mfma_f32_16x16x32_bf16(
              af0[m][kc], bfA[n][kc], acc[m][n], 0, 0, 0);
    __builtin_amdgcn_s_setprio(0);
    __builtin_amdgcn_s_barrier();

    // ---- phase 1: reads bfB(4); STAGE_B(t+1); bar; MFMA Q01
#pragma unroll
    for (int n = 0; n < 2; ++n) {
      bfB[n][0] = *(const bf16x8*)(sBb + bbase + (2 + n) * 1024 + kidx0);
      bfB[n][1] = *(const bf16x8*)(sBb + bbase + (2 + n) * 1024 + kidx1);
    }
    if (t < 63) { STAGE_B(b ^ 1, kk + 64); }
    __builtin_amdgcn_sched_barrier(0);
    __builtin_amdgcn_s_barrier();
    __builtin_amdgcn_s_setprio(1);
#pragma unroll
    for (int m = 0; m < 4; ++m)
#pragma unroll
      for (int n = 0; n < 2; ++n)
#pragma unroll
        for (int kc = 0; kc < 2; ++kc)
          acc[m][2 + n] = __builtin_amdgcn_mfma_f32_16x16x32_bf16(
              af0[m][kc], bfB[n][kc], acc[m][2 + n], 0, 0, 0);
    __builtin_amdgcn_s_setprio(0);
    __builtin_amdgcn_s_barrier();

    // ---- phase 2: reads af1(8); bar; MFMA Q11
#pragma unroll
    for (int m = 0; m < 4; ++m) {
      af1[m][0] = *(const bf16x8*)(sAb + abase + (4 + m) * 1024 + kidx0);
      af1[m][1] = *(const bf16x8*)(sAb + abase + (4 + m) * 1024 + kidx1);
    }
    __builtin_amdgcn_sched_barrier(0);
    __builtin_amdgcn_s_barrier();
    __builtin_amdgcn_s_setprio(1);
#pragma unroll
    for (int m = 0; m < 4; ++m)
#pragma unroll
      for (int n = 0; n < 2; ++n)
#pragma unroll
        for (int kc = 0; kc < 2; ++kc)
          acc[4 + m][2 + n] = __builtin_amdgcn_mfma_f32_16x16x32_bf16(
              af1[m][kc], bfB[n][kc], acc[4 + m][2 + n], 0, 0, 0);
    __builtin_amdgcn_s_setprio(0);
    __builtin_amdgcn_s_barrier();

    // ---- phase 3: vmcnt(0) (loads 2-3 phases old); bar; MFMA Q10 (regs only)
    if (t < 63) { asm volatile("s_waitcnt vmcnt(0)" ::: "memory"); }
    __builtin_amdgcn_s_barrier();
    __builtin_amdgcn_s_setprio(1);
#pragma unroll
    for (int m = 0; m < 4; ++m)
#pragma unroll
      for (int n = 0; n < 2; ++n)
#pragma unroll
        for (int kc = 0; kc < 2; ++kc)
          acc[4 + m][n] = __builtin_amdgcn_mfma_f32_16x16x32_bf16(
              af1[m][kc], bfA[n][kc], acc[4 + m][n], 0, 0, 0);
    __builtin_amdgcn_s_setprio(0);
    __builtin_amdgcn_s_barrier();
  }

  // epilogue: C/D layout col=lane&15, row=(lane>>4)*4+reg (m89-verified)
  const int fr = lane & 15;
  const int fq = lane >> 4;
  const int growbase = bm * 256 + wr * 128;
  const int gcolbase = bn * 256 + wc * 64;
#pragma unroll
  for (int ni = 0; ni < 4; ++ni) {
    const int col = gcolbase + ni * 16 + fr;
    const float bv = bias[col];
#pragma unroll
    for (int mi = 0; mi < 8; ++mi) {
      float* cp = C + (size_t)(growbase + mi * 16 + fq * 4) * N_DIM + col;
#pragma unroll
      for (int r = 0; r < 4; ++r)
        cp[(size_t)r * N_DIM] = acc[mi][ni][r] + bv;
    }
  }
}

// ---------------- fallback (only if ws too small): fused naive fp32 ---------
__global__ void k_fallback(const float* __restrict__ x, const int* __restrict__ wp,
                           const float* __restrict__ wsc, const float* __restrict__ wbs,
                           const float* __restrict__ bias, float* __restrict__ y) {
  const int m = blockIdx.x;
  const int n = blockIdx.y * 256 + threadIdx.x;
  const float* xr = x + (size_t)m * K_DIM;
  const int gbase = n * (K_DIM / 8);
  float acc = 0.f;
  for (int g = 0; g < K_DIM / 8; ++g) {
    i32x4 p = *(const i32x4*)(wp + (size_t)(gbase + g) * 4);
    const float s = wsc[gbase + g];
    const float b = wbs[gbase + g];
    const float* xk = xr + g * 8;
#pragma unroll
    for (int j = 0; j < 4; ++j) {
      acc += ((float)(p[j] & 15)        * s + b) * xk[2 * j];
      acc += ((float)((p[j] >> 4) & 15) * s + b) * xk[2 * j + 1];
    }
  }
  y[(size_t)m * N_DIM + n] = acc + bias[n];
}

extern "C" void kernel_launch(void* const* d_in, const int* in_sizes, int n_in,
                              void* d_out, int out_size, void* d_ws, size_t ws_size,
                              hipStream_t stream) {
  const float* x    = (const float*)d_in[0];
  const int*   wp   = (const int*)d_in[1];
  const float* wsc  = (const float*)d_in[2];
  const float* wbs  = (const float*)d_in[3];
  const float* bias = (const float*)d_in[4];
  float* y = (float*)d_out;

  const size_t wbytes = (size_t)N_DIM * K_DIM * sizeof(ushort);
  const size_t xbytes = (size_t)M_DIM * K_DIM * sizeof(ushort);

  if (ws_size >= wbytes + xbytes) {
    ushort* Wbf = (ushort*)d_ws;
    ushort* Xbf = (ushort*)((char*)d_ws + wbytes);
    k_dequant_w<<<NGROUPS / 256, 256, 0, stream>>>(wp, wsc, wbs, Wbf);
    k_cvt_x<<<(M_DIM * K_DIM / 8) / 256, 256, 0, stream>>>(x, Xbf);
    k_gemm_8ph<<<16 * 16, 512, 0, stream>>>(Xbf, Wbf, bias, y);
  } else {
    k_fallback<<<dim3(M_DIM, N_DIM / 256), 256, 0, stream>>>(x, wp, wsc, wbs, bias, y);
  }
}

// Round 8
// 286.295 us; speedup vs baseline: 1.0514x; 1.0374x over previous
//
#include <hip/hip_runtime.h>
#include <hip/hip_bf16.h>
#include <stdint.h>

#define M_DIM 4096
#define N_DIM 4096
#define K_DIM 4096
#define NGROUPS (N_DIM * K_DIM / 8)

typedef __attribute__((ext_vector_type(4))) float f32x4;
typedef __attribute__((ext_vector_type(8))) short bf16x8;
typedef __attribute__((ext_vector_type(4))) int   i32x4;

__device__ __forceinline__ ushort f2bf(float f) {
  union { float f; uint32_t u; } v; v.f = f;
  uint32_t r = v.u + 0x7FFFu + ((v.u >> 16) & 1u);
  return (ushort)(r >> 16);
}

// ---------------- pre-pass 1: dequant 4-bit W -> bf16 [N][K] ----------------
__global__ void k_dequant_w(const int* __restrict__ wp, const float* __restrict__ wsc,
                            const float* __restrict__ wbs, ushort* __restrict__ W) {
  const int g = blockIdx.x * 256 + threadIdx.x;
  i32x4 p = *(const i32x4*)(wp + (size_t)g * 4);
  const float s = wsc[g];
  const float b = wbs[g];
  bf16x8 o;
#pragma unroll
  for (int j = 0; j < 4; ++j) {
    const float lo = (float)(p[j] & 15)        * s + b;
    const float hi = (float)((p[j] >> 4) & 15) * s + b;
    o[2 * j]     = (short)f2bf(lo);
    o[2 * j + 1] = (short)f2bf(hi);
  }
  *(bf16x8*)(W + (size_t)g * 8) = o;
}

// ---------------- pre-pass 2: cast x fp32 -> bf16 [M][K] ----------------
__global__ void k_cvt_x(const float* __restrict__ x, ushort* __restrict__ X) {
  const int t = blockIdx.x * 256 + threadIdx.x;
  f32x4 a = *(const f32x4*)(x + (size_t)t * 8);
  f32x4 b = *(const f32x4*)(x + (size_t)t * 8 + 4);
  bf16x8 o;
#pragma unroll
  for (int j = 0; j < 4; ++j) {
    o[j]     = (short)f2bf(a[j]);
    o[4 + j] = (short)f2bf(b[j]);
  }
  *(bf16x8*)(X + (size_t)t * 8) = o;
}

// ---------------- main: 256x256, BK=64, 8 waves, counted-vmcnt pipeline -----
// T4 applied: the prefetch queue is NEVER drained in the main loop. Tile t+2
// stages into the dbuf being read by tile t (B at ph2 after B(t) fully read,
// A at ph3 after A(t) fully read — barrier-separated). The only staging wait
// is vmcnt(8) at ph3: in-order vmem retirement means "all but the 8 newest
// (= t+2's own stages) done" => tile t+1's loads landed; t+2's stay in
// flight. Tail (t>=62): vmcnt(0), loads long-landed. Swizzle as R4
// (measured conflicts == 0).

#define GLD(src, dst) __builtin_amdgcn_global_load_lds(                        \
    (const __attribute__((address_space(1))) void*)(src),                      \
    (__attribute__((address_space(3))) void*)(dst), 16, 0, 0)

__global__ __launch_bounds__(512, 2) void k_gemm_8ph(
    const ushort* __restrict__ A, const ushort* __restrict__ B,
    const float* __restrict__ bias, float* __restrict__ C) {
  __shared__ ushort sA[2][256 * 64];
  __shared__ ushort sB[2][256 * 64];
  const int tid  = threadIdx.x;
  const int lane = tid & 63;
  const int wid  = tid >> 6;
  const int wr   = wid >> 2;   // 0..1  (M)
  const int wc   = wid & 3;    // 0..3  (N)
  const int bm = blockIdx.x >> 4;
  const int bn = blockIdx.x & 15;

  const ushort* Ab = A + (size_t)bm * 256 * K_DIM;
  const ushort* Bb = B + (size_t)bn * 256 * K_DIM;

  // staging: 4 chunks/thread/operand; source col-chunk pre-swizzled.
  const int srow = tid >> 3;
  const int scc  = (tid & 7) ^ ((tid >> 3) & 7);
  const int dofs = (tid >> 6) * 64 * 8;  // wave-uniform chunk base (ushorts)

  // fragment read geometry (swizzled)
  const int l15   = lane & 15;
  const int kx    = (lane >> 4) * 8;
  const int xsw   = (lane & 7) << 3;
  const int kidx0 = (0 * 32 + kx) ^ xsw;
  const int kidx1 = (1 * 32 + kx) ^ xsw;
  const int abase = (wr * 128 + l15) * 64;
  const int bbase = (wc * 64 + l15) * 64;

  f32x4 acc[8][4] = {};

#define STAGE_A(buf, kko)                                                      \
  _Pragma("unroll") for (int j = 0; j < 4; ++j)                                \
      GLD(Ab + (size_t)(j * 64 + srow) * K_DIM + (kko) + scc * 8,              \
          &sA[buf][j * 4096 + dofs]);
#define STAGE_B(buf, kko)                                                      \
  _Pragma("unroll") for (int j = 0; j < 4; ++j)                                \
      GLD(Bb + (size_t)(j * 64 + srow) * K_DIM + (kko) + scc * 8,              \
          &sB[buf][j * 4096 + dofs]);

  // prologue: stage tiles 0 (dbuf0) and 1 (dbuf1); confirm tile 0 only.
  STAGE_A(0, 0);
  STAGE_B(0, 0);
  STAGE_A(1, 64);
  STAGE_B(1, 64);
  asm volatile("s_waitcnt vmcnt(8)" ::: "memory");   // tile 0 landed; tile 1 in flight
  __builtin_amdgcn_sched_barrier(0);
  __builtin_amdgcn_s_barrier();

  bf16x8 af0[4][2], af1[4][2], bfA[2][2], bfB[2][2];

  for (int t = 0; t < 64; ++t) {
    const int d  = t & 1;
    const int kk = t * 64;
    const ushort* sAb = sA[d];
    const ushort* sBb = sB[d];

    // ---- phase 0: reads af0(8)+bfA(4); bar; MFMA Q00
#pragma unroll
    for (int m = 0; m < 4; ++m) {
      af0[m][0] = *(const bf16x8*)(sAb + abase + m * 1024 + kidx0);
      af0[m][1] = *(const bf16x8*)(sAb + abase + m * 1024 + kidx1);
    }
#pragma unroll
    for (int n = 0; n < 2; ++n) {
      bfA[n][0] = *(const bf16x8*)(sBb + bbase + n * 1024 + kidx0);
      bfA[n][1] = *(const bf16x8*)(sBb + bbase + n * 1024 + kidx1);
    }
    __builtin_amdgcn_sched_barrier(0);
    __builtin_amdgcn_s_barrier();
    __builtin_amdgcn_s_setprio(1);
#pragma unroll
    for (int m = 0; m < 4; ++m)
#pragma unroll
      for (int n = 0; n < 2; ++n)
#pragma unroll
        for (int kc = 0; kc < 2; ++kc)
          acc[m][n] = __builtin_amdgcn_mfma_f32_16x16x32_bf16(
              af0[m][kc], bfA[n][kc], acc[m][n], 0, 0, 0);
    __builtin_amdgcn_s_setprio(0);
    __builtin_amdgcn_s_barrier();

    // ---- phase 1: reads bfB(4); bar; MFMA Q01   [B(t) fully read after this]
#pragma unroll
    for (int n = 0; n < 2; ++n) {
      bfB[n][0] = *(const bf16x8*)(sBb + bbase + (2 + n) * 1024 + kidx0);
      bfB[n][1] = *(const bf16x8*)(sBb + bbase + (2 + n) * 1024 + kidx1);
    }
    __builtin_amdgcn_sched_barrier(0);
    __builtin_amdgcn_s_barrier();
    __builtin_amdgcn_s_setprio(1);
#pragma unroll
    for (int m = 0; m < 4; ++m)
#pragma unroll
      for (int n = 0; n < 2; ++n)
#pragma unroll
        for (int kc = 0; kc < 2; ++kc)
          acc[m][2 + n] = __builtin_amdgcn_mfma_f32_16x16x32_bf16(
              af0[m][kc], bfB[n][kc], acc[m][2 + n], 0, 0, 0);
    __builtin_amdgcn_s_setprio(0);
    __builtin_amdgcn_s_barrier();

    // ---- phase 2: reads af1(8); STAGE_B(t+2 -> dbuf d, B(t) region free);
    //      bar; MFMA Q11
#pragma unroll
    for (int m = 0; m < 4; ++m) {
      af1[m][0] = *(const bf16x8*)(sAb + abase + (4 + m) * 1024 + kidx0);
      af1[m][1] = *(const bf16x8*)(sAb + abase + (4 + m) * 1024 + kidx1);
    }
    if (t < 62) { STAGE_B(d, kk + 128); }
    __builtin_amdgcn_sched_barrier(0);
    __builtin_amdgcn_s_barrier();
    __builtin_amdgcn_s_setprio(1);
#pragma unroll
    for (int m = 0; m < 4; ++m)
#pragma unroll
      for (int n = 0; n < 2; ++n)
#pragma unroll
        for (int kc = 0; kc < 2; ++kc)
          acc[4 + m][2 + n] = __builtin_amdgcn_mfma_f32_16x16x32_bf16(
              af1[m][kc], bfB[n][kc], acc[4 + m][2 + n], 0, 0, 0);
    __builtin_amdgcn_s_setprio(0);
    __builtin_amdgcn_s_barrier();

    // ---- phase 3: STAGE_A(t+2 -> dbuf d, A(t) region free); counted wait
    //      confirming tile t+1 (t+2's 8 stages stay in flight); bar; MFMA Q10
    if (t < 62) {
      STAGE_A(d, kk + 128);
      asm volatile("s_waitcnt vmcnt(8)" ::: "memory");
    } else {
      asm volatile("s_waitcnt vmcnt(0)" ::: "memory");
    }
    __builtin_amdgcn_sched_barrier(0);
    __builtin_amdgcn_s_barrier();
    __builtin_amdgcn_s_setprio(1);
#pragma unroll
    for (int m = 0; m < 4; ++m)
#pragma unroll
      for (int n = 0; n < 2; ++n)
#pragma unroll
        for (int kc = 0; kc < 2; ++kc)
          acc[4 + m][n] = __builtin_amdgcn_mfma_f32_16x16x32_bf16(
              af1[m][kc], bfA[n][kc], acc[4 + m][n], 0, 0, 0);
    __builtin_amdgcn_s_setprio(0);
    __builtin_amdgcn_s_barrier();
  }

  // epilogue: C/D layout col=lane&15, row=(lane>>4)*4+reg (m89-verified)
  const int fr = lane & 15;
  const int fq = lane >> 4;
  const int growbase = bm * 256 + wr * 128;
  const int gcolbase = bn * 256 + wc * 64;
#pragma unroll
  for (int ni = 0; ni < 4; ++ni) {
    const int col = gcolbase + ni * 16 + fr;
    const float bv = bias[col];
#pragma unroll
    for (int mi = 0; mi < 8; ++mi) {
      float* cp = C + (size_t)(growbase + mi * 16 + fq * 4) * N_DIM + col;
#pragma unroll
      for (int r = 0; r < 4; ++r)
        cp[(size_t)r * N_DIM] = acc[mi][ni][r] + bv;
    }
  }
}

// ---------------- fallback (only if ws too small): fused naive fp32 ---------
__global__ void k_fallback(const float* __restrict__ x, const int* __restrict__ wp,
                           const float* __restrict__ wsc, const float* __restrict__ wbs,
                           const float* __restrict__ bias, float* __restrict__ y) {
  const int m = blockIdx.x;
  const int n = blockIdx.y * 256 + threadIdx.x;
  const float* xr = x + (size_t)m * K_DIM;
  const int gbase = n * (K_DIM / 8);
  float acc = 0.f;
  for (int g = 0; g < K_DIM / 8; ++g) {
    i32x4 p = *(const i32x4*)(wp + (size_t)(gbase + g) * 4);
    const float s = wsc[gbase + g];
    const float b = wbs[gbase + g];
    const float* xk = xr + g * 8;
#pragma unroll
    for (int j = 0; j < 4; ++j) {
      acc += ((float)(p[j] & 15)        * s + b) * xk[2 * j];
      acc += ((float)((p[j] >> 4) & 15) * s + b) * xk[2 * j + 1];
    }
  }
  y[(size_t)m * N_DIM + n] = acc + bias[n];
}

extern "C" void kernel_launch(void* const* d_in, const int* in_sizes, int n_in,
                              void* d_out, int out_size, void* d_ws, size_t ws_size,
                              hipStream_t stream) {
  const float* x    = (const float*)d_in[0];
  const int*   wp   = (const int*)d_in[1];
  const float* wsc  = (const float*)d_in[2];
  const float* wbs  = (const float*)d_in[3];
  const float* bias = (const float*)d_in[4];
  float* y = (float*)d_out;

  const size_t wbytes = (size_t)N_DIM * K_DIM * sizeof(ushort);
  const size_t xbytes = (size_t)M_DIM * K_DIM * sizeof(ushort);

  if (ws_size >= wbytes + xbytes) {
    ushort* Wbf = (ushort*)d_ws;
    ushort* Xbf = (ushort*)((char*)d_ws + wbytes);
    k_dequant_w<<<NGROUPS / 256, 256, 0, stream>>>(wp, wsc, wbs, Wbf);
    k_cvt_x<<<(M_DIM * K_DIM / 8) / 256, 256, 0, stream>>>(x, Xbf);
    k_gemm_8ph<<<16 * 16, 512, 0, stream>>>(Xbf, Wbf, bias, y);
  } else {
    k_fallback<<<dim3(M_DIM, N_DIM / 256), 256, 0, stream>>>(x, wp, wsc, wbs, bias, y);
  }
}